// Round 7
// baseline (184.693 us; speedup 1.0000x reference)
//
#include <hip/hip_runtime.h>
#include <cstdint>
#include <cstddef>

typedef short bf16x8 __attribute__((ext_vector_type(8)));
typedef float f32x4 __attribute__((ext_vector_type(4)));

#define DM 1024
#define NHEADS 16
#define NGROUPS 4
#define DK 64
#define BATCH 2
#define SEQ 2048
#define MROWS 4096

#define QB_ELEMS   ((size_t)BATCH*NHEADS*SEQ*DK)   // 4M shorts
#define KB_ELEMS   ((size_t)BATCH*NGROUPS*SEQ*DK)  // 1M
#define VT_ELEMS   KB_ELEMS                        // 1M  ([b][g][d][col] permuted)
#define XC_ELEMS   ((size_t)MROWS*DM)              // 4M  (xbf, later reused as ctx)
#define WQKV_ELEMS ((size_t)1536*DM)
#define WO_ELEMS   ((size_t)DM*DM)

#define SCL_Q 0.180336880f    // (1/sqrt(64)) * log2(e), folded into Q

__device__ __forceinline__ ushort f2bf(float f) {          // RNE
    union { float f; uint32_t u; } a; a.f = f;
    uint32_t u = a.u;
    return (ushort)((u + 0x7FFFu + ((u >> 16) & 1u)) >> 16);
}

// async global->LDS, 16B/lane; LDS dest = wave-uniform base + lane*16
__device__ __forceinline__ void gll16(const void* g, void* l) {
    __builtin_amdgcn_global_load_lds((const __attribute__((address_space(1))) void*)g,
                                     (__attribute__((address_space(3))) void*)l, 16, 0, 0);
}

// 64x64 fp32->bf16 transpose tile through LDS (tl must be float[64][65])
__device__ __forceinline__ void transpose_tile(
        const float* __restrict__ src, int src_ld, ushort* __restrict__ dst,
        int r0, int c0, int tid, float (*tl)[65])
{
    const int rr = tid >> 4, cc = (tid & 15) * 4;
#pragma unroll
    for (int p = 0; p < 4; p++) {
        int r = rr + p * 16;
        float4 v = *(const float4*)(src + (size_t)(r0 + r) * src_ld + c0 + cc);
        tl[cc + 0][r] = v.x; tl[cc + 1][r] = v.y;
        tl[cc + 2][r] = v.z; tl[cc + 3][r] = v.w;
    }
    __syncthreads();
#pragma unroll
    for (int p = 0; p < 4; p++) {
        int c = rr + p * 16;
        ushort4 o;
        o.x = f2bf(tl[c][cc + 0]); o.y = f2bf(tl[c][cc + 1]);
        o.z = f2bf(tl[c][cc + 2]); o.w = f2bf(tl[c][cc + 3]);
        *(ushort4*)(dst + (size_t)(c0 + c) * 1024 + r0 + cc) = o;
    }
}

// ---------------------------------------------------------------------------
// Prep (512 blocks, strided over 897 units): W_Q/W_K/W_V/W_O transposes,
// x fp32->bf16, bias concat.
// ---------------------------------------------------------------------------
__global__ __launch_bounds__(256) void gqa_prep_kernel(
        const float* __restrict__ x,
        const float* __restrict__ WQ, const float* __restrict__ WK,
        const float* __restrict__ WV, const float* __restrict__ WO,
        const float* __restrict__ bQ, const float* __restrict__ bK,
        const float* __restrict__ bV,
        ushort* __restrict__ xbf, ushort* __restrict__ WqkvT,
        ushort* __restrict__ WoT, float* __restrict__ bcat)
{
    __shared__ float tl[64][65];
    const int tid = threadIdx.x;
    for (int u = blockIdx.x; u < 897; u += 512) {
        if (u < 256) {            // WQ [d][c] -> WqkvT rows c
            transpose_tile(WQ, 1024, WqkvT, (u >> 4) * 64, (u & 15) * 64, tid, tl);
        } else if (u < 320) {     // WK[g] -> rows 1024+g*64
            int t = u - 256, g = t >> 4;
            transpose_tile(WK + (size_t)g * 65536, 64,
                           WqkvT + (size_t)(1024 + g * 64) * 1024,
                           (t & 15) * 64, 0, tid, tl);
        } else if (u < 384) {     // WV[g] -> rows 1280+g*64
            int t = u - 320, g = t >> 4;
            transpose_tile(WV + (size_t)g * 65536, 64,
                           WqkvT + (size_t)(1280 + g * 64) * 1024,
                           (t & 15) * 64, 0, tid, tl);
        } else if (u < 640) {     // WO -> WoT
            int t = u - 384;
            transpose_tile(WO, 1024, WoT, (t >> 4) * 64, (t & 15) * 64, tid, tl);
        } else if (u < 896) {     // x fp32 -> bf16
            int cid = u - 640;
            const float* xs = x + (size_t)cid * 16384;
            ushort* xd = xbf + (size_t)cid * 16384;
#pragma unroll
            for (int p = 0; p < 16; p++) {
                float4 v = *(const float4*)(xs + p * 1024 + tid * 4);
                ushort4 o = { f2bf(v.x), f2bf(v.y), f2bf(v.z), f2bf(v.w) };
                *(ushort4*)(xd + p * 1024 + tid * 4) = o;
            }
        } else {                  // bias concat
            for (int k = tid; k < 1536; k += 256) {
                float v = (k < 1024) ? bQ[k] : (k < 1280 ? bK[k - 1024] : bV[k - 1280]);
                bcat[k] = v;
            }
        }
        __syncthreads();          // LDS reuse across units
    }
}

// ---------------------------------------------------------------------------
// GEMM: C[4096][16*NJ*32] = A[4096][1024]*B (+bias), BT[N][1024].
// Tile 128 x (NJ*32), BK=64, 4 waves (2x2, wave 64 x NJ*16), gll16 dbuf,
// 1 barrier/iter. Grid is always 32x16 = 512 tiles -> perfectly balanced at
// 2 blocks/CU. NJ=3: QKV (N=1536); NJ=2: O-proj (N=1024).
// ---------------------------------------------------------------------------
template<int NJ, bool QKV_EPI>
__global__ __launch_bounds__(256, 2) void gqa_gemm_kernel(
        const ushort* __restrict__ A, const ushort* __restrict__ BT,
        const float* __restrict__ bias, float* __restrict__ outF,
        ushort* __restrict__ Qb, ushort* __restrict__ Kb,
        ushort* __restrict__ Vtg)
{
    constexpr int BNT = NJ * 32;                 // tile width
    __shared__ ushort smem[16384 + NJ * 4096];   // As dbuf + Bs dbuf
    ushort* As = smem;                           // 2 bufs x 8192 ushorts
    ushort* Bs = smem + 16384;                   // 2 bufs x NJ*2048 ushorts

    const int tid = threadIdx.x;
    const int i = blockIdx.x;
    const int xcd = i & 7, slot = i >> 3;        // slot 0..63
    const int bm = (slot >> 4) * 8 + xcd;        // 0..31
    const int bn = slot & 15;                    // 0..15
    const int wave = tid >> 6, lane = tid & 63;
    const int wm = (wave & 1) * 64, wn = (wave >> 1) * (NJ * 16);
    const int lr = lane & 15, lq = lane >> 4;
    const int swz = lr & 7;

    const ushort* srcA[4]; int dstOffA[4];
    const ushort* srcB[NJ]; int dstOffB[NJ];
#pragma unroll
    for (int p = 0; p < 4; p++) {
        int slt = p * 256 + tid;
        int row = slt >> 3, cb = (slt & 7) ^ (row & 7);
        srcA[p] = A + (size_t)(bm * 128 + row) * 1024 + cb * 8;
        dstOffA[p] = p * 2048 + wave * 512;
    }
#pragma unroll
    for (int p = 0; p < NJ; p++) {
        int slt = p * 256 + tid;
        int row = slt >> 3, cb = (slt & 7) ^ (row & 7);
        srcB[p] = BT + (size_t)(bn * BNT + row) * 1024 + cb * 8;
        dstOffB[p] = p * 2048 + wave * 512;
    }

    f32x4 acc[4][NJ];
#pragma unroll
    for (int ii = 0; ii < 4; ii++)
#pragma unroll
        for (int j = 0; j < NJ; j++) acc[ii][j] = (f32x4){0.f, 0.f, 0.f, 0.f};

#pragma unroll
    for (int p = 0; p < 4; p++) gll16(srcA[p], &As[dstOffA[p]]);
#pragma unroll
    for (int p = 0; p < NJ; p++) gll16(srcB[p], &Bs[dstOffB[p]]);

    for (int kt = 0; kt < 16; kt++) {
        __syncthreads();
        if (kt < 15) {
            int buf = (kt + 1) & 1, ko = (kt + 1) * 64;
#pragma unroll
            for (int p = 0; p < 4; p++)
                gll16(srcA[p] + ko, &As[buf * 8192 + dstOffA[p]]);
#pragma unroll
            for (int p = 0; p < NJ; p++)
                gll16(srcB[p] + ko, &Bs[buf * (NJ * 2048) + dstOffB[p]]);
        }
        const ushort* as = As + (kt & 1) * 8192;
        const ushort* bs = Bs + (kt & 1) * (NJ * 2048);
        bf16x8 af[2][4], bfr[2][NJ];
#pragma unroll
        for (int kh = 0; kh < 2; kh++) {
#pragma unroll
            for (int ii = 0; ii < 4; ii++)
                af[kh][ii] = *(const bf16x8*)&as[(wm + ii * 16 + lr) * 64 + ((kh * 4 + lq) ^ swz) * 8];
#pragma unroll
            for (int j = 0; j < NJ; j++)
                bfr[kh][j] = *(const bf16x8*)&bs[(wn + j * 16 + lr) * 64 + ((kh * 4 + lq) ^ swz) * 8];
        }
#pragma unroll
        for (int kh = 0; kh < 2; kh++)
#pragma unroll
            for (int ii = 0; ii < 4; ii++)
#pragma unroll
                for (int j = 0; j < NJ; j++)
                    acc[ii][j] = __builtin_amdgcn_mfma_f32_16x16x32_bf16(af[kh][ii], bfr[kh][j], acc[ii][j], 0, 0, 0);
    }

#pragma unroll
    for (int ii = 0; ii < 4; ii++) {
        int mg = bm * 128 + wm + ii * 16 + lq * 4;
        int b = mg >> 11, s = mg & 2047;
#pragma unroll
        for (int j = 0; j < NJ; j++) {
            int cg = bn * BNT + wn + j * 16 + lr;
            float bv = bias[cg];
            if constexpr (QKV_EPI) {
                int d = cg & 63;
                if (cg < 1024) {
                    int h = cg >> 6;
                    ushort* dst = Qb + ((size_t)(b * NHEADS + h) * SEQ + s) * DK + d;
#pragma unroll
                    for (int r = 0; r < 4; r++)
                        dst[r * DK] = f2bf((acc[ii][j][r] + bv) * SCL_Q);
                } else if (cg < 1280) {
                    int g = (cg - 1024) >> 6;
                    ushort* dst = Kb + ((size_t)(b * NGROUPS + g) * SEQ + s) * DK + d;
#pragma unroll
                    for (int r = 0; r < 4; r++) dst[r * DK] = f2bf(acc[ii][j][r] + bv);
                } else {
                    int g = (cg - 1280) >> 6;
                    // permuted V^T column: 4-key group kg -> position (kg&3)*2+(kg>>2)
                    int s4 = s >> 2, kg = s4 & 7;
                    int col = ((s4 >> 3) << 5) + (((((kg & 3) << 1) | (kg >> 2))) << 2);
                    ushort4 pk;
                    pk.x = f2bf(acc[ii][j][0] + bv); pk.y = f2bf(acc[ii][j][1] + bv);
                    pk.z = f2bf(acc[ii][j][2] + bv); pk.w = f2bf(acc[ii][j][3] + bv);
                    *(ushort4*)(Vtg + ((size_t)(b * NGROUPS + g) * DK + d) * SEQ + col) = pk;
                }
            } else {
#pragma unroll
                for (int r = 0; r < 4; r++)
                    outF[(size_t)(mg + r) * DM + cg] = acc[ii][j][r] + bv;
            }
        }
    }
}

// ---------------------------------------------------------------------------
// Attention (R7): 512 blocks x 256 threads, XCD-local (bg = i&7).
// Block = 128 q x full key sweep in 128-key tiles (16 iters). 4 waves 2x2:
// wq in {0,1} (64 q), wt in {0,1} (64-t stripe).
// NO LDS STAGING: K/V panels are 256 KB each and XCD-L2-resident (R6 FETCH
// = 6 MB proves it) -> kf/vf MFMA fragments are read DIRECTLY from global
// (common-mistake #7: staging L2-fit data is pure overhead). The old LDS
// XOR swizzles cancel: direct addresses are the natural unswizzled ones,
// so fragment data is bitwise identical to R4's post-LDS values.
// ZERO barriers in the main loop; waves fully independent; latency hidden
// by ILP (16 indep loads/iter) + ~3 blocks/CU TLP. One barrier before the
// (unchanged) LDS combine. launch_bounds(256,2): no R5 spill trap.
// ---------------------------------------------------------------------------
__global__ __launch_bounds__(256, 2) void gqa_attn_kernel(
        const ushort* __restrict__ Qb, const ushort* __restrict__ Kb,
        const ushort* __restrict__ Vtg, ushort* __restrict__ ctx)
{
    __shared__ float comb[2][4096];      // 32 KB combine buffer
    __shared__ float accX[128];

    const int tid = threadIdx.x, wave = tid >> 6, lane = tid & 63;
    const int lr = lane & 15, lq = lane >> 4;
    const int wq = wave & 1, wt = wave >> 1;
    const int i = blockIdx.x;
    const int bg = i & 7, s2 = i >> 3;
    const int qt = s2 & 15, h = s2 >> 4;
    const int b = bg >> 2, g = bg & 3, hg = g * 4 + h;

    const ushort* Qh = Qb  + (size_t)(b * NHEADS  + hg) * SEQ * DK;
    const ushort* Kg = Kb  + (size_t)(b * NGROUPS + g)  * SEQ * DK;
    const ushort* Vg = Vtg + (size_t)(b * NGROUPS + g)  * DK * SEQ;

    const int s0 = qt * 128 + wq * 64;
    const int tb = wt * 64;              // wave's t-stripe base within tile

    bf16x8 qf[4][2];
#pragma unroll
    for (int qs = 0; qs < 4; qs++)
#pragma unroll
        for (int kh = 0; kh < 2; kh++)
            qf[qs][kh] = *(const bf16x8*)(Qh + (size_t)(s0 + qs * 16 + lr) * DK + kh * 32 + lq * 8);

    f32x4 of[4][4];
#pragma unroll
    for (int qs = 0; qs < 4; qs++)
#pragma unroll
        for (int j = 0; j < 4; j++) of[qs][j] = (f32x4){0.f, 0.f, 0.f, 0.f};
    f32x4 accL[4];
#pragma unroll
    for (int qs = 0; qs < 4; qs++) accL[qs] = (f32x4){0.f, 0.f, 0.f, 0.f};

    bf16x8 ones;
#pragma unroll
    for (int k = 0; k < 8; k++) ones[k] = (short)0x3F80;

    // per-lane base pointers (uniform strides per iteration)
    const ushort* kbase = Kg + (size_t)(tb + lr) * DK + lq * 8;
    const ushort* vbase = Vg + (size_t)lr * SEQ + wt * 64 + lq * 8;

    for (int it = 0; it < 16; it++) {
        const ushort* kp = kbase + (size_t)it * 128 * DK;
        const ushort* vp = vbase + it * 128;

        // K fragments direct from L2 (natural layout; swizzles cancel)
        bf16x8 kf[4][2];
#pragma unroll
        for (int nt = 0; nt < 4; nt++)
#pragma unroll
            for (int kh = 0; kh < 2; kh++)
                kf[nt][kh] = *(const bf16x8*)(kp + (size_t)nt * 16 * DK + kh * 32);

        // V^T fragments direct from L2 (column-permuted layout as stored)
        bf16x8 vf[4][2];
#pragma unroll
        for (int j = 0; j < 4; j++)
#pragma unroll
            for (int kk = 0; kk < 2; kk++)
                vf[j][kk] = *(const bf16x8*)(vp + (size_t)j * 16 * SEQ + kk * 32);

        // S^T[t][q] over the wave's 64-t stripe (Q pre-scaled -> log2 domain)
        f32x4 sc[4][4];
        __builtin_amdgcn_s_setprio(1);
#pragma unroll
        for (int qs = 0; qs < 4; qs++)
#pragma unroll
            for (int nt = 0; nt < 4; nt++) {
                f32x4 s = (f32x4){0.f, 0.f, 0.f, 0.f};
                s = __builtin_amdgcn_mfma_f32_16x16x32_bf16(kf[nt][0], qf[qs][0], s, 0, 0, 0);
                s = __builtin_amdgcn_mfma_f32_16x16x32_bf16(kf[nt][1], qf[qs][1], s, 0, 0, 0);
                sc[qs][nt] = s;
            }
        __builtin_amdgcn_s_setprio(0);

        // exp2 -> truncate-pack into two K=32 B-frags per qs; sums via ones-MFMA
        union PF { bf16x8 v; uint32_t w[4]; };
        PF pf[4][2];
#pragma unroll
        for (int qs = 0; qs < 4; qs++) {
#pragma unroll
            for (int nt = 0; nt < 4; nt++) {
                union { float f; uint32_t u; } e0, e1, e2, e3;
                e0.f = __builtin_amdgcn_exp2f(sc[qs][nt][0]);
                e1.f = __builtin_amdgcn_exp2f(sc[qs][nt][1]);
                e2.f = __builtin_amdgcn_exp2f(sc[qs][nt][2]);
                e3.f = __builtin_amdgcn_exp2f(sc[qs][nt][3]);
                pf[qs][nt >> 1].w[(nt & 1) * 2 + 0] = __builtin_amdgcn_perm(e1.u, e0.u, 0x07060302u);
                pf[qs][nt >> 1].w[(nt & 1) * 2 + 1] = __builtin_amdgcn_perm(e3.u, e2.u, 0x07060302u);
            }
        }

        __builtin_amdgcn_s_setprio(1);
#pragma unroll
        for (int qs = 0; qs < 4; qs++) {
            accL[qs] = __builtin_amdgcn_mfma_f32_16x16x32_bf16(ones, pf[qs][0].v, accL[qs], 0, 0, 0);
            accL[qs] = __builtin_amdgcn_mfma_f32_16x16x32_bf16(ones, pf[qs][1].v, accL[qs], 0, 0, 0);
        }
        // O^T[d][q] += V^T(stripe) . P
#pragma unroll
        for (int qs = 0; qs < 4; qs++)
#pragma unroll
            for (int j = 0; j < 4; j++) {
                of[qs][j] = __builtin_amdgcn_mfma_f32_16x16x32_bf16(vf[j][0], pf[qs][0].v, of[qs][j], 0, 0, 0);
                of[qs][j] = __builtin_amdgcn_mfma_f32_16x16x32_bf16(vf[j][1], pf[qs][1].v, of[qs][j], 0, 0, 0);
            }
        __builtin_amdgcn_s_setprio(0);
    }

    // ---- combine t-halves (wt=1 -> LDS -> wt=0 adds) ----
    __syncthreads();
    if (wt == 1) {
        float* cw = &comb[wq][0];
#pragma unroll
        for (int qs = 0; qs < 4; qs++)
#pragma unroll
            for (int j = 0; j < 4; j++)
                *(f32x4*)&cw[(qs * 4 + j) * 256 + lane * 4] = of[qs][j];
        if (lq == 0) {
#pragma unroll
            for (int qs = 0; qs < 4; qs++) accX[(wq * 4 + qs) * 16 + lr] = accL[qs][0];
        }
    }
    __syncthreads();
    if (wt == 0) {
        const float* cw = &comb[wq][0];
        float inv[4];
#pragma unroll
        for (int qs = 0; qs < 4; qs++)
            inv[qs] = 1.0f / (accL[qs][0] + accX[(wq * 4 + qs) * 16 + lr]);
        ushort* cbp = ctx + (size_t)b * SEQ * DM;
#pragma unroll
        for (int qs = 0; qs < 4; qs++) {
            int s = s0 + qs * 16 + lr;
#pragma unroll
            for (int j = 0; j < 4; j++) {
                f32x4 o2 = of[qs][j] + *(const f32x4*)&cw[(qs * 4 + j) * 256 + lane * 4];
                ushort4 o;
                o.x = f2bf(o2[0] * inv[qs]);
                o.y = f2bf(o2[1] * inv[qs]);
                o.z = f2bf(o2[2] * inv[qs]);
                o.w = f2bf(o2[3] * inv[qs]);
                *(ushort4*)(cbp + (size_t)s * DM + hg * 64 + j * 16 + lq * 4) = o;
            }
        }
    }
}

// ---------------------------------------------------------------------------
extern "C" void kernel_launch(void* const* d_in, const int* in_sizes, int n_in,
                              void* d_out, int out_size, void* d_ws, size_t ws_size,
                              hipStream_t stream) {
    const float* x  = (const float*)d_in[0];
    const float* WQ = (const float*)d_in[1];
    const float* bQ = (const float*)d_in[2];
    const float* WK = (const float*)d_in[3];
    const float* bK = (const float*)d_in[4];
    const float* WV = (const float*)d_in[5];
    const float* bV = (const float*)d_in[6];
    const float* WO = (const float*)d_in[7];
    const float* bO = (const float*)d_in[8];

    ushort* Qb    = (ushort*)d_ws;
    ushort* Kb    = Qb + QB_ELEMS;
    ushort* Vtg   = Kb + KB_ELEMS;
    ushort* xc    = Vtg + VT_ELEMS;       // xbf (QKV input), later reused as ctx
    ushort* WqkvT = xc + XC_ELEMS;
    ushort* WoT   = WqkvT + WQKV_ELEMS;
    float*  bcat  = (float*)(WoT + WO_ELEMS);

    gqa_prep_kernel<<<512, 256, 0, stream>>>(x, WQ, WK, WV, WO, bQ, bK, bV,
                                             xc, WqkvT, WoT, bcat);
    // QKV: 32x16 = 512 tiles of 128x96 (N=1536), 2 blocks/CU balanced
    gqa_gemm_kernel<3, true><<<512, 256, 0, stream>>>(
        xc, WqkvT, bcat, nullptr, Qb, Kb, Vtg);
    // attention: 512 blocks x 4 waves, no K/V staging (L2-direct)
    gqa_attn_kernel<<<512, 256, 0, stream>>>(Qb, Kb, Vtg, xc);
    // O-proj: 32x16 = 512 tiles of 128x64 (N=1024), 2 blocks/CU balanced
    gqa_gemm_kernel<2, false><<<512, 256, 0, stream>>>(
        xc, WoT, bO, (float*)d_out, nullptr, nullptr, nullptr);
}

// Round 8
// 183.267 us; speedup vs baseline: 1.0078x; 1.0078x over previous
//
#include <hip/hip_runtime.h>
#include <cstdint>
#include <cstddef>

typedef short bf16x8 __attribute__((ext_vector_type(8)));
typedef float f32x4 __attribute__((ext_vector_type(4)));

#define DM 1024
#define NHEADS 16
#define NGROUPS 4
#define DK 64
#define BATCH 2
#define SEQ 2048
#define MROWS 4096

#define QB_ELEMS   ((size_t)BATCH*NHEADS*SEQ*DK)   // 4M shorts
#define KB_ELEMS   ((size_t)BATCH*NGROUPS*SEQ*DK)  // 1M
#define VT_ELEMS   KB_ELEMS                        // 1M  ([b][g][d][col] permuted)
#define XC_ELEMS   ((size_t)MROWS*DM)              // 4M  (xbf, later reused as ctx)
#define WQKV_ELEMS ((size_t)1536*DM)
#define WO_ELEMS   ((size_t)DM*DM)

#define SCL_Q 0.180336880f    // (1/sqrt(64)) * log2(e), folded into Q

__device__ __forceinline__ ushort f2bf(float f) {          // RNE
    union { float f; uint32_t u; } a; a.f = f;
    uint32_t u = a.u;
    return (ushort)((u + 0x7FFFu + ((u >> 16) & 1u)) >> 16);
}

// async global->LDS, 16B/lane; LDS dest = wave-uniform base + lane*16
__device__ __forceinline__ void gll16(const void* g, void* l) {
    __builtin_amdgcn_global_load_lds((const __attribute__((address_space(1))) void*)g,
                                     (__attribute__((address_space(3))) void*)l, 16, 0, 0);
}

// 64x64 fp32->bf16 transpose tile through LDS (tl must be float[64][65])
__device__ __forceinline__ void transpose_tile(
        const float* __restrict__ src, int src_ld, ushort* __restrict__ dst,
        int r0, int c0, int tid, float (*tl)[65])
{
    const int rr = tid >> 4, cc = (tid & 15) * 4;
#pragma unroll
    for (int p = 0; p < 4; p++) {
        int r = rr + p * 16;
        float4 v = *(const float4*)(src + (size_t)(r0 + r) * src_ld + c0 + cc);
        tl[cc + 0][r] = v.x; tl[cc + 1][r] = v.y;
        tl[cc + 2][r] = v.z; tl[cc + 3][r] = v.w;
    }
    __syncthreads();
#pragma unroll
    for (int p = 0; p < 4; p++) {
        int c = rr + p * 16;
        ushort4 o;
        o.x = f2bf(tl[c][cc + 0]); o.y = f2bf(tl[c][cc + 1]);
        o.z = f2bf(tl[c][cc + 2]); o.w = f2bf(tl[c][cc + 3]);
        *(ushort4*)(dst + (size_t)(c0 + c) * 1024 + r0 + cc) = o;
    }
}

// ---------------------------------------------------------------------------
// Prep (641 blocks): W_Q/W_K/W_V transposes -> WqkvT, x fp32->bf16, bias.
// (W_O transpose rides inside the QKV GEMM launch.)
// ---------------------------------------------------------------------------
__global__ __launch_bounds__(256) void gqa_prep_kernel(
        const float* __restrict__ x,
        const float* __restrict__ WQ, const float* __restrict__ WK,
        const float* __restrict__ WV,
        const float* __restrict__ bQ, const float* __restrict__ bK,
        const float* __restrict__ bV,
        ushort* __restrict__ xbf, ushort* __restrict__ WqkvT,
        float* __restrict__ bcat)
{
    __shared__ float tl[64][65];
    const int bid = blockIdx.x, tid = threadIdx.x;
    if (bid < 256) {            // WQ [d][c] -> WqkvT rows c
        transpose_tile(WQ, 1024, WqkvT, (bid >> 4) * 64, (bid & 15) * 64, tid, tl);
    } else if (bid < 320) {     // WK[g] [d][k] -> rows 1024+g*64
        int t = bid - 256, g = t >> 4;
        transpose_tile(WK + (size_t)g * 1024 * 64, 64,
                       WqkvT + (size_t)(1024 + g * 64) * 1024,
                       (t & 15) * 64, 0, tid, tl);
    } else if (bid < 384) {     // WV[g] -> rows 1280+g*64
        int t = bid - 320, g = t >> 4;
        transpose_tile(WV + (size_t)g * 1024 * 64, 64,
                       WqkvT + (size_t)(1280 + g * 64) * 1024,
                       (t & 15) * 64, 0, tid, tl);
    } else if (bid < 640) {     // x convert
        int cid = bid - 384;
        const float* xs = x + (size_t)cid * 16384;
        ushort* xd = xbf + (size_t)cid * 16384;
#pragma unroll
        for (int p = 0; p < 16; p++) {
            float4 v = *(const float4*)(xs + p * 1024 + tid * 4);
            ushort4 o = { f2bf(v.x), f2bf(v.y), f2bf(v.z), f2bf(v.w) };
            *(ushort4*)(xd + p * 1024 + tid * 4) = o;
        }
    } else {
        for (int i = tid; i < 1536; i += 256) {
            float v = (i < 1024) ? bQ[i] : (i < 1280 ? bK[i - 1024] : bV[i - 1280]);
            bcat[i] = v;
        }
    }
}

// ---------------------------------------------------------------------------
// GEMM (R8): C[4096][N] = A[4096][1024]*B (+bias), BT[N][1024].
// 128x128 tile, BK=64, 4 waves (2x2, wave 64x64, acc 4x4), gll16 dbuf,
// 1 barrier/iter, 64 KB LDS, launch_bounds(256,2).
// RIDERS: first 256 blocks transpose W_O (QKV launch only).
// KSPLIT: each (bm,bn) tile is computed by TWO blocks over K-halves of 512,
// partials atomicAdd'ed into outF (harness zeroes out); bias added by the
// k-lower half only. Fixes O-proj's 1-block/CU exposure (256 -> 512 blocks).
// ---------------------------------------------------------------------------
template<bool QKV_EPI, int BN, bool RIDERS, bool KSPLIT>
__global__ __launch_bounds__(256, 2) void gqa_gemm_kernel(
        const ushort* __restrict__ A, const ushort* __restrict__ BT,
        const float* __restrict__ bias, float* __restrict__ outF,
        ushort* __restrict__ Qb, ushort* __restrict__ Kb, ushort* __restrict__ Vtg,
        const float* __restrict__ WO, ushort* __restrict__ WoT)
{
    __shared__ ushort smem[4][8192];     // As buf0/1, Bs buf0/1 (64 KB)
    const int tid = threadIdx.x;
    int i = blockIdx.x;

    if constexpr (RIDERS) {
        if (i < 256) {   // W_O transpose rider
            float (*tl)[65] = (float(*)[65])&smem[0][0];
            transpose_tile(WO, 1024, WoT, (i >> 4) * 64, (i & 15) * 64, tid, tl);
            return;
        }
        i -= 256;
    }

    const int xcd = i & 7;
    int slot = i >> 3;
    int kh0 = 0;                         // K-base (elements) for this block
    if constexpr (KSPLIT) {
        kh0 = (slot & 1) * 512;          // adjacent blocks share (bm,bn) pair? no:
        slot >>= 1;                      // pair (2s,2s+1) -> same tile, same XCD
    }
    const int bm = (slot / BN) * 8 + xcd;
    const int bn = slot % BN;
    const int wave = tid >> 6, lane = tid & 63;
    const int wm = (wave & 1) * 64, wn = (wave >> 1) * 64;
    const int lr = lane & 15, lq = lane >> 4;
    const int swz = lr & 7;

    // staging: 128 rows x 64 cols per matrix per buffer = 1024 16B chunks,
    // 4 chunks/thread; row = slot>>3, chunk XOR-swizzled by row&7.
    const ushort* srcA[4]; const ushort* srcB[4]; int dstOff[4];
#pragma unroll
    for (int p = 0; p < 4; p++) {
        int slt = p * 256 + tid;
        int row = slt >> 3, cb = (slt & 7) ^ (row & 7);
        srcA[p] = A  + (size_t)(bm * 128 + row) * 1024 + kh0 + cb * 8;
        srcB[p] = BT + (size_t)(bn * 128 + row) * 1024 + kh0 + cb * 8;
        dstOff[p] = p * 2048 + wave * 512;
    }

    f32x4 acc[4][4];
#pragma unroll
    for (int ii = 0; ii < 4; ii++)
#pragma unroll
        for (int j = 0; j < 4; j++) acc[ii][j] = (f32x4){0.f, 0.f, 0.f, 0.f};

#pragma unroll
    for (int p = 0; p < 4; p++) {
        gll16(srcA[p], &smem[0][dstOff[p]]);
        gll16(srcB[p], &smem[2][dstOff[p]]);
    }

    constexpr int NKT = KSPLIT ? 8 : 16;
    for (int kt = 0; kt < NKT; kt++) {
        __syncthreads();
        if (kt < NKT - 1) {
            int buf = (kt + 1) & 1, ko = (kt + 1) * 64;
#pragma unroll
            for (int p = 0; p < 4; p++) {
                gll16(srcA[p] + ko, &smem[buf][dstOff[p]]);
                gll16(srcB[p] + ko, &smem[2 + buf][dstOff[p]]);
            }
        }
        const ushort* as = smem[kt & 1];
        const ushort* bs = smem[2 + (kt & 1)];
        bf16x8 af[2][4], bfr[2][4];
#pragma unroll
        for (int kh = 0; kh < 2; kh++) {
#pragma unroll
            for (int ii = 0; ii < 4; ii++)
                af[kh][ii] = *(const bf16x8*)&as[(wm + ii * 16 + lr) * 64 + ((kh * 4 + lq) ^ swz) * 8];
#pragma unroll
            for (int j = 0; j < 4; j++)
                bfr[kh][j] = *(const bf16x8*)&bs[(wn + j * 16 + lr) * 64 + ((kh * 4 + lq) ^ swz) * 8];
        }
#pragma unroll
        for (int kh = 0; kh < 2; kh++)
#pragma unroll
            for (int ii = 0; ii < 4; ii++)
#pragma unroll
                for (int j = 0; j < 4; j++)
                    acc[ii][j] = __builtin_amdgcn_mfma_f32_16x16x32_bf16(af[kh][ii], bfr[kh][j], acc[ii][j], 0, 0, 0);
    }

#pragma unroll
    for (int ii = 0; ii < 4; ii++) {
        int mg = bm * 128 + wm + ii * 16 + lq * 4;
        int b = mg >> 11, s = mg & 2047;
#pragma unroll
        for (int j = 0; j < 4; j++) {
            int cg = bn * 128 + wn + j * 16 + lr;
            float bv = bias[cg];
            if constexpr (QKV_EPI) {
                int d = cg & 63;
                if (cg < 1024) {
                    int h = cg >> 6;
                    ushort* dst = Qb + ((size_t)(b * NHEADS + h) * SEQ + s) * DK + d;
#pragma unroll
                    for (int r = 0; r < 4; r++)
                        dst[r * DK] = f2bf((acc[ii][j][r] + bv) * SCL_Q);
                } else if (cg < 1280) {
                    int g = (cg - 1024) >> 6;
                    ushort* dst = Kb + ((size_t)(b * NGROUPS + g) * SEQ + s) * DK + d;
#pragma unroll
                    for (int r = 0; r < 4; r++) dst[r * DK] = f2bf(acc[ii][j][r] + bv);
                } else {
                    int g = (cg - 1280) >> 6;
                    // permuted V^T column: 4-key group kg -> position (kg&3)*2+(kg>>2)
                    int s4 = s >> 2, kg = s4 & 7;
                    int col = ((s4 >> 3) << 5) + (((((kg & 3) << 1) | (kg >> 2))) << 2);
                    ushort4 pk;
                    pk.x = f2bf(acc[ii][j][0] + bv); pk.y = f2bf(acc[ii][j][1] + bv);
                    pk.z = f2bf(acc[ii][j][2] + bv); pk.w = f2bf(acc[ii][j][3] + bv);
                    *(ushort4*)(Vtg + ((size_t)(b * NGROUPS + g) * DK + d) * SEQ + col) = pk;
                }
            } else if constexpr (KSPLIT) {
                float badd = (kh0 == 0) ? bv : 0.f;
#pragma unroll
                for (int r = 0; r < 4; r++)
                    atomicAdd(&outF[(size_t)(mg + r) * DM + cg], acc[ii][j][r] + badd);
            } else {
#pragma unroll
                for (int r = 0; r < 4; r++)
                    outF[(size_t)(mg + r) * DM + cg] = acc[ii][j][r] + bv;
            }
        }
    }
}

// ---------------------------------------------------------------------------
// Attention (R1/R4-exact, best known 43.5 us): 512 blocks, XCD-local.
// Block = 128 q x full key sweep in 128-key tiles (16 iters). 4 waves 2x2.
// gll16 dbuf LDS 64 KB (K 128x64, V^T 64x128), 2 blocks/CU.
// ---------------------------------------------------------------------------
__global__ __launch_bounds__(256, 2) void gqa_attn_kernel(
        const ushort* __restrict__ Qb, const ushort* __restrict__ Kb,
        const ushort* __restrict__ Vtg, ushort* __restrict__ ctx)
{
    __shared__ ushort Ks[2][128 * 64];   // 32 KB
    __shared__ ushort Vs[2][64 * 128];   // 32 KB

    const int tid = threadIdx.x, wave = tid >> 6, lane = tid & 63;
    const int lr = lane & 15, lq = lane >> 4;
    const int swz = lr & 7;
    const int wq = wave & 1, wt = wave >> 1;
    const int i = blockIdx.x;
    const int bg = i & 7, s2 = i >> 3;
    const int qt = s2 & 15, h = s2 >> 4;
    const int b = bg >> 2, g = bg & 3, hg = g * 4 + h;

    const ushort* Qh = Qb  + (size_t)(b * NHEADS  + hg) * SEQ * DK;
    const ushort* Kg = Kb  + (size_t)(b * NGROUPS + g)  * SEQ * DK;
    const ushort* Vg = Vtg + (size_t)(b * NGROUPS + g)  * DK * SEQ;

    const int s0 = qt * 128 + wq * 64;
    const int tb = wt * 64;              // wave's t-stripe base within tile

    bf16x8 qf[4][2];
#pragma unroll
    for (int qs = 0; qs < 4; qs++)
#pragma unroll
        for (int kh = 0; kh < 2; kh++)
            qf[qs][kh] = *(const bf16x8*)(Qh + (size_t)(s0 + qs * 16 + lr) * DK + kh * 32 + lq * 8);

    // staging: K 4 slots (row = slot>>3 in 0..127, 8 chunks/row);
    //          V 4 slots (row = slot>>4 in 0..63, 16 chunks/row, XOR low-3)
    const ushort* srcK[4]; const ushort* srcV[4]; int dstOff[4];
#pragma unroll
    for (int p = 0; p < 4; p++) {
        int slt = p * 256 + tid;
        int krow = slt >> 3, kcb = (slt & 7) ^ (krow & 7);
        srcK[p] = Kg + (size_t)krow * DK + kcb * 8;
        int vrow = slt >> 4, vc = slt & 15;
        int vcb = (vc & 8) | ((vc ^ vrow) & 7);
        srcV[p] = Vg + (size_t)vrow * SEQ + vcb * 8;
        dstOff[p] = (p * 256 + wave * 64) * 8;   // ushort offset; lane*8 added by HW
    }

    f32x4 of[4][4];
#pragma unroll
    for (int qs = 0; qs < 4; qs++)
#pragma unroll
        for (int j = 0; j < 4; j++) of[qs][j] = (f32x4){0.f, 0.f, 0.f, 0.f};
    f32x4 accL[4];
#pragma unroll
    for (int qs = 0; qs < 4; qs++) accL[qs] = (f32x4){0.f, 0.f, 0.f, 0.f};

    bf16x8 ones;
#pragma unroll
    for (int k = 0; k < 8; k++) ones[k] = (short)0x3F80;

#pragma unroll
    for (int p = 0; p < 4; p++) {
        gll16(srcK[p], &Ks[0][dstOff[p]]);
        gll16(srcV[p], &Vs[0][dstOff[p]]);
    }

    for (int it = 0; it < 16; it++) {
        __syncthreads();
        if (it < 15) {
            int buf = (it + 1) & 1, t0 = (it + 1) * 128;
#pragma unroll
            for (int p = 0; p < 4; p++) {
                gll16(srcK[p] + (size_t)t0 * DK, &Ks[buf][dstOff[p]]);
                gll16(srcV[p] + t0, &Vs[buf][dstOff[p]]);
            }
        }
        const ushort* ks = Ks[it & 1];
        const ushort* vs = Vs[it & 1];

        bf16x8 kf[4][2];
#pragma unroll
        for (int nt = 0; nt < 4; nt++)
#pragma unroll
            for (int kh = 0; kh < 2; kh++)
                kf[nt][kh] = *(const bf16x8*)&ks[(tb + nt * 16 + lr) * 64 + ((kh * 4 + lq) ^ swz) * 8];

        bf16x8 vf[4][2];
#pragma unroll
        for (int j = 0; j < 4; j++)
#pragma unroll
            for (int kk = 0; kk < 2; kk++)
                vf[j][kk] = *(const bf16x8*)&vs[(j * 16 + lr) * 128 + (wt * 8 + ((kk * 4 + lq) ^ swz)) * 8];

        // S^T[t][q] over the wave's 64-t stripe (Q pre-scaled -> log2 domain)
        f32x4 sc[4][4];
#pragma unroll
        for (int qs = 0; qs < 4; qs++)
#pragma unroll
            for (int nt = 0; nt < 4; nt++) {
                f32x4 s = (f32x4){0.f, 0.f, 0.f, 0.f};
                s = __builtin_amdgcn_mfma_f32_16x16x32_bf16(kf[nt][0], qf[qs][0], s, 0, 0, 0);
                s = __builtin_amdgcn_mfma_f32_16x16x32_bf16(kf[nt][1], qf[qs][1], s, 0, 0, 0);
                sc[qs][nt] = s;
            }

        // exp2 -> truncate-pack into two K=32 B-frags per qs; sums via ones-MFMA
        union PF { bf16x8 v; uint32_t w[4]; };
        PF pf[4][2];
#pragma unroll
        for (int qs = 0; qs < 4; qs++) {
#pragma unroll
            for (int nt = 0; nt < 4; nt++) {
                union { float f; uint32_t u; } e0, e1, e2, e3;
                e0.f = __builtin_amdgcn_exp2f(sc[qs][nt][0]);
                e1.f = __builtin_amdgcn_exp2f(sc[qs][nt][1]);
                e2.f = __builtin_amdgcn_exp2f(sc[qs][nt][2]);
                e3.f = __builtin_amdgcn_exp2f(sc[qs][nt][3]);
                pf[qs][nt >> 1].w[(nt & 1) * 2 + 0] = __builtin_amdgcn_perm(e1.u, e0.u, 0x07060302u);
                pf[qs][nt >> 1].w[(nt & 1) * 2 + 1] = __builtin_amdgcn_perm(e3.u, e2.u, 0x07060302u);
            }
            accL[qs] = __builtin_amdgcn_mfma_f32_16x16x32_bf16(ones, pf[qs][0].v, accL[qs], 0, 0, 0);
            accL[qs] = __builtin_amdgcn_mfma_f32_16x16x32_bf16(ones, pf[qs][1].v, accL[qs], 0, 0, 0);
        }

        // O^T[d][q] += V^T(stripe) · P
#pragma unroll
        for (int qs = 0; qs < 4; qs++)
#pragma unroll
            for (int j = 0; j < 4; j++) {
                of[qs][j] = __builtin_amdgcn_mfma_f32_16x16x32_bf16(vf[j][0], pf[qs][0].v, of[qs][j], 0, 0, 0);
                of[qs][j] = __builtin_amdgcn_mfma_f32_16x16x32_bf16(vf[j][1], pf[qs][1].v, of[qs][j], 0, 0, 0);
            }
    }

    // ---- combine t-halves (wt=1 -> LDS overlay -> wt=0 adds) ----
    __syncthreads();                       // all staging reads done; overlay safe
    float* comb = (float*)&Ks[0][0];       // 32 KB: [wq][(qs*4+j)*256 + lane*4]
    float* accX = (float*)&Vs[0][0];       // [ (wq*4+qs)*16 + lr ]
    if (wt == 1) {
        float* cw = comb + wq * 4096;
#pragma unroll
        for (int qs = 0; qs < 4; qs++)
#pragma unroll
            for (int j = 0; j < 4; j++)
                *(f32x4*)&cw[(qs * 4 + j) * 256 + lane * 4] = of[qs][j];
        if (lq == 0) {
#pragma unroll
            for (int qs = 0; qs < 4; qs++) accX[(wq * 4 + qs) * 16 + lr] = accL[qs][0];
        }
    }
    __syncthreads();
    if (wt == 0) {
        const float* cw = comb + wq * 4096;
        float inv[4];
#pragma unroll
        for (int qs = 0; qs < 4; qs++)
            inv[qs] = 1.0f / (accL[qs][0] + accX[(wq * 4 + qs) * 16 + lr]);
        ushort* cbp = ctx + (size_t)b * SEQ * DM;
#pragma unroll
        for (int qs = 0; qs < 4; qs++) {
            int s = s0 + qs * 16 + lr;
#pragma unroll
            for (int j = 0; j < 4; j++) {
                f32x4 o2 = of[qs][j] + *(const f32x4*)&cw[(qs * 4 + j) * 256 + lane * 4];
                ushort4 o;
                o.x = f2bf(o2[0] * inv[qs]);
                o.y = f2bf(o2[1] * inv[qs]);
                o.z = f2bf(o2[2] * inv[qs]);
                o.w = f2bf(o2[3] * inv[qs]);
                *(ushort4*)(cbp + (size_t)s * DM + hg * 64 + j * 16 + lq * 4) = o;
            }
        }
    }
}

// ---------------------------------------------------------------------------
extern "C" void kernel_launch(void* const* d_in, const int* in_sizes, int n_in,
                              void* d_out, int out_size, void* d_ws, size_t ws_size,
                              hipStream_t stream) {
    const float* x  = (const float*)d_in[0];
    const float* WQ = (const float*)d_in[1];
    const float* bQ = (const float*)d_in[2];
    const float* WK = (const float*)d_in[3];
    const float* bK = (const float*)d_in[4];
    const float* WV = (const float*)d_in[5];
    const float* bV = (const float*)d_in[6];
    const float* WO = (const float*)d_in[7];
    const float* bO = (const float*)d_in[8];

    ushort* Qb    = (ushort*)d_ws;
    ushort* Kb    = Qb + QB_ELEMS;
    ushort* Vtg   = Kb + KB_ELEMS;
    ushort* xc    = Vtg + VT_ELEMS;       // xbf (QKV input), later reused as ctx
    ushort* WqkvT = xc + XC_ELEMS;
    ushort* WoT   = WqkvT + WQKV_ELEMS;
    float*  bcat  = (float*)(WoT + WO_ELEMS);

    gqa_prep_kernel<<<641, 256, 0, stream>>>(x, WQ, WK, WV, bQ, bK, bV,
                                             xc, WqkvT, bcat);
    // QKV: 256 riders + 32x12 = 640 blocks (128x128 tiles, N=1536)
    gqa_gemm_kernel<true, 12, true, false><<<640, 256, 0, stream>>>(
        xc, WqkvT, bcat, nullptr, Qb, Kb, Vtg, WO, WoT);
    gqa_attn_kernel<<<512, 256, 0, stream>>>(Qb, Kb, Vtg, xc);
    // O-proj: split-K x2 -> 512 blocks (2/CU), atomicAdd epilogue
    gqa_gemm_kernel<false, 8, false, true><<<512, 256, 0, stream>>>(
        xc, WoT, bO, (float*)d_out, nullptr, nullptr, nullptr, nullptr, nullptr);
}

// Round 9
// 155.725 us; speedup vs baseline: 1.1860x; 1.1769x over previous
//
#include <hip/hip_runtime.h>
#include <cstdint>
#include <cstddef>

typedef short bf16x8 __attribute__((ext_vector_type(8)));
typedef float f32x4 __attribute__((ext_vector_type(4)));

#define DM 1024
#define NHEADS 16
#define NGROUPS 4
#define DK 64
#define BATCH 2
#define SEQ 2048
#define MROWS 4096

#define QB_ELEMS   ((size_t)BATCH*NHEADS*SEQ*DK)   // 4M shorts
#define KB_ELEMS   ((size_t)BATCH*NGROUPS*SEQ*DK)  // 1M
#define VT_ELEMS   KB_ELEMS                        // 1M  ([b][g][d][col] permuted)
#define XC_ELEMS   ((size_t)MROWS*DM)              // 4M  (xbf, later reused as ctx)
#define WQKV_ELEMS ((size_t)1536*DM)
#define WO_ELEMS   ((size_t)DM*DM)

#define SCL_Q 0.180336880f    // (1/sqrt(64)) * log2(e), folded into Q

__device__ __forceinline__ ushort f2bf(float f) {          // RNE
    union { float f; uint32_t u; } a; a.f = f;
    uint32_t u = a.u;
    return (ushort)((u + 0x7FFFu + ((u >> 16) & 1u)) >> 16);
}

// async global->LDS, 16B/lane; LDS dest = wave-uniform base + lane*16
__device__ __forceinline__ void gll16(const void* g, void* l) {
    __builtin_amdgcn_global_load_lds((const __attribute__((address_space(1))) void*)g,
                                     (__attribute__((address_space(3))) void*)l, 16, 0, 0);
}

// 64x64 fp32->bf16 transpose tile through LDS (tl must be float[64][65])
__device__ __forceinline__ void transpose_tile(
        const float* __restrict__ src, int src_ld, ushort* __restrict__ dst,
        int r0, int c0, int tid, float (*tl)[65])
{
    const int rr = tid >> 4, cc = (tid & 15) * 4;
#pragma unroll
    for (int p = 0; p < 4; p++) {
        int r = rr + p * 16;
        float4 v = *(const float4*)(src + (size_t)(r0 + r) * src_ld + c0 + cc);
        tl[cc + 0][r] = v.x; tl[cc + 1][r] = v.y;
        tl[cc + 2][r] = v.z; tl[cc + 3][r] = v.w;
    }
    __syncthreads();
#pragma unroll
    for (int p = 0; p < 4; p++) {
        int c = rr + p * 16;
        ushort4 o;
        o.x = f2bf(tl[c][cc + 0]); o.y = f2bf(tl[c][cc + 1]);
        o.z = f2bf(tl[c][cc + 2]); o.w = f2bf(tl[c][cc + 3]);
        *(ushort4*)(dst + (size_t)(c0 + c) * 1024 + r0 + cc) = o;
    }
}

// ---------------------------------------------------------------------------
// Prep (641 blocks): W_Q/W_K/W_V transposes -> WqkvT, x fp32->bf16, bias.
// (W_O transpose rides inside the QKV GEMM launch.)  [R1-exact]
// ---------------------------------------------------------------------------
__global__ __launch_bounds__(256) void gqa_prep_kernel(
        const float* __restrict__ x,
        const float* __restrict__ WQ, const float* __restrict__ WK,
        const float* __restrict__ WV,
        const float* __restrict__ bQ, const float* __restrict__ bK,
        const float* __restrict__ bV,
        ushort* __restrict__ xbf, ushort* __restrict__ WqkvT,
        float* __restrict__ bcat)
{
    __shared__ float tl[64][65];
    const int bid = blockIdx.x, tid = threadIdx.x;
    if (bid < 256) {            // WQ [d][c] -> WqkvT rows c
        transpose_tile(WQ, 1024, WqkvT, (bid >> 4) * 64, (bid & 15) * 64, tid, tl);
    } else if (bid < 320) {     // WK[g] [d][k] -> rows 1024+g*64
        int t = bid - 256, g = t >> 4;
        transpose_tile(WK + (size_t)g * 1024 * 64, 64,
                       WqkvT + (size_t)(1024 + g * 64) * 1024,
                       (t & 15) * 64, 0, tid, tl);
    } else if (bid < 384) {     // WV[g] -> rows 1280+g*64
        int t = bid - 320, g = t >> 4;
        transpose_tile(WV + (size_t)g * 1024 * 64, 64,
                       WqkvT + (size_t)(1280 + g * 64) * 1024,
                       (t & 15) * 64, 0, tid, tl);
    } else if (bid < 640) {     // x convert
        int cid = bid - 384;
        const float* xs = x + (size_t)cid * 16384;
        ushort* xd = xbf + (size_t)cid * 16384;
#pragma unroll
        for (int p = 0; p < 16; p++) {
            float4 v = *(const float4*)(xs + p * 1024 + tid * 4);
            ushort4 o = { f2bf(v.x), f2bf(v.y), f2bf(v.z), f2bf(v.w) };
            *(ushort4*)(xd + p * 1024 + tid * 4) = o;
        }
    } else {
        for (int i = tid; i < 1536; i += 256) {
            float v = (i < 1024) ? bQ[i] : (i < 1280 ? bK[i - 1024] : bV[i - 1280]);
            bcat[i] = v;
        }
    }
}

// ---------------------------------------------------------------------------
// QKV GEMM (R1-exact): C[4096][1536] = A*B (+bias), BT[1536][1024].
// 128x128 tile, BK=64, 4 waves (2x2, wave 64x64, acc 4x4), gll16 dbuf,
// 1 barrier/iter, 64 KB LDS, launch_bounds(256,2).
// RIDERS: first 256 blocks transpose W_O.
// ---------------------------------------------------------------------------
template<int BN>
__global__ __launch_bounds__(256, 2) void gqa_qkv_kernel(
        const ushort* __restrict__ A, const ushort* __restrict__ BT,
        const float* __restrict__ bias,
        ushort* __restrict__ Qb, ushort* __restrict__ Kb, ushort* __restrict__ Vtg,
        const float* __restrict__ WO, ushort* __restrict__ WoT)
{
    __shared__ ushort smem[4][8192];     // As buf0/1, Bs buf0/1 (64 KB)
    const int tid = threadIdx.x;
    int i = blockIdx.x;

    if (i < 256) {   // W_O transpose rider
        float (*tl)[65] = (float(*)[65])&smem[0][0];
        transpose_tile(WO, 1024, WoT, (i >> 4) * 64, (i & 15) * 64, tid, tl);
        return;
    }
    i -= 256;

    const int xcd = i & 7, slot = i >> 3;
    const int bm = (slot / BN) * 8 + xcd;
    const int bn = slot % BN;
    const int wave = tid >> 6, lane = tid & 63;
    const int wm = (wave & 1) * 64, wn = (wave >> 1) * 64;
    const int lr = lane & 15, lq = lane >> 4;
    const int swz = lr & 7;

    const ushort* srcA[4]; const ushort* srcB[4]; int dstOff[4];
#pragma unroll
    for (int p = 0; p < 4; p++) {
        int slt = p * 256 + tid;
        int row = slt >> 3, cb = (slt & 7) ^ (row & 7);
        srcA[p] = A  + (size_t)(bm * 128 + row) * 1024 + cb * 8;
        srcB[p] = BT + (size_t)(bn * 128 + row) * 1024 + cb * 8;
        dstOff[p] = p * 2048 + wave * 512;
    }

    f32x4 acc[4][4];
#pragma unroll
    for (int ii = 0; ii < 4; ii++)
#pragma unroll
        for (int j = 0; j < 4; j++) acc[ii][j] = (f32x4){0.f, 0.f, 0.f, 0.f};

#pragma unroll
    for (int p = 0; p < 4; p++) {
        gll16(srcA[p], &smem[0][dstOff[p]]);
        gll16(srcB[p], &smem[2][dstOff[p]]);
    }

    for (int kt = 0; kt < 16; kt++) {
        __syncthreads();
        if (kt < 15) {
            int buf = (kt + 1) & 1, ko = (kt + 1) * 64;
#pragma unroll
            for (int p = 0; p < 4; p++) {
                gll16(srcA[p] + ko, &smem[buf][dstOff[p]]);
                gll16(srcB[p] + ko, &smem[2 + buf][dstOff[p]]);
            }
        }
        const ushort* as = smem[kt & 1];
        const ushort* bs = smem[2 + (kt & 1)];
        bf16x8 af[2][4], bfr[2][4];
#pragma unroll
        for (int kh = 0; kh < 2; kh++) {
#pragma unroll
            for (int ii = 0; ii < 4; ii++)
                af[kh][ii] = *(const bf16x8*)&as[(wm + ii * 16 + lr) * 64 + ((kh * 4 + lq) ^ swz) * 8];
#pragma unroll
            for (int j = 0; j < 4; j++)
                bfr[kh][j] = *(const bf16x8*)&bs[(wn + j * 16 + lr) * 64 + ((kh * 4 + lq) ^ swz) * 8];
        }
#pragma unroll
        for (int kh = 0; kh < 2; kh++)
#pragma unroll
            for (int ii = 0; ii < 4; ii++)
#pragma unroll
                for (int j = 0; j < 4; j++)
                    acc[ii][j] = __builtin_amdgcn_mfma_f32_16x16x32_bf16(af[kh][ii], bfr[kh][j], acc[ii][j], 0, 0, 0);
    }

#pragma unroll
    for (int ii = 0; ii < 4; ii++) {
        int mg = bm * 128 + wm + ii * 16 + lq * 4;
        int b = mg >> 11, s = mg & 2047;
#pragma unroll
        for (int j = 0; j < 4; j++) {
            int cg = bn * 128 + wn + j * 16 + lr;
            float bv = bias[cg];
            int d = cg & 63;
            if (cg < 1024) {
                int h = cg >> 6;
                ushort* dst = Qb + ((size_t)(b * NHEADS + h) * SEQ + s) * DK + d;
#pragma unroll
                for (int r = 0; r < 4; r++)
                    dst[r * DK] = f2bf((acc[ii][j][r] + bv) * SCL_Q);
            } else if (cg < 1280) {
                int g = (cg - 1024) >> 6;
                ushort* dst = Kb + ((size_t)(b * NGROUPS + g) * SEQ + s) * DK + d;
#pragma unroll
                for (int r = 0; r < 4; r++) dst[r * DK] = f2bf(acc[ii][j][r] + bv);
            } else {
                int g = (cg - 1280) >> 6;
                // permuted V^T column: 4-key group kg -> position (kg&3)*2+(kg>>2)
                int s4 = s >> 2, kg = s4 & 7;
                int col = ((s4 >> 3) << 5) + (((((kg & 3) << 1) | (kg >> 2))) << 2);
                ushort4 pk;
                pk.x = f2bf(acc[ii][j][0] + bv); pk.y = f2bf(acc[ii][j][1] + bv);
                pk.z = f2bf(acc[ii][j][2] + bv); pk.w = f2bf(acc[ii][j][3] + bv);
                *(ushort4*)(Vtg + ((size_t)(b * NGROUPS + g) * DK + d) * SEQ + col) = pk;
            }
        }
    }
}

// ---------------------------------------------------------------------------
// O-proj GEMM (R4-exact, NJ=2): C[4096][1024] = ctx*WoT + bO.
// Tile 128x64, BK=64, 4 waves (2x2, wave 64x32, acc 4x2), gll16 dbuf,
// 1 barrier/iter, 48 KB LDS -> 512 blocks at 2/CU (fixes R1's 1-block/CU
// exposure, no atomics). HW-validated in R4/R6.
// ---------------------------------------------------------------------------
__global__ __launch_bounds__(256, 2) void gqa_oproj_kernel(
        const ushort* __restrict__ A, const ushort* __restrict__ BT,
        const float* __restrict__ bias, float* __restrict__ outF)
{
    constexpr int NJ = 2;
    constexpr int BNT = NJ * 32;                 // tile width 64
    __shared__ ushort smem[16384 + NJ * 4096];   // As dbuf + Bs dbuf (48 KB)
    ushort* As = smem;                           // 2 bufs x 8192 ushorts
    ushort* Bs = smem + 16384;                   // 2 bufs x NJ*2048 ushorts

    const int tid = threadIdx.x;
    const int i = blockIdx.x;
    const int xcd = i & 7, slot = i >> 3;        // slot 0..63
    const int bm = (slot >> 4) * 8 + xcd;        // 0..31
    const int bn = slot & 15;                    // 0..15
    const int wave = tid >> 6, lane = tid & 63;
    const int wm = (wave & 1) * 64, wn = (wave >> 1) * (NJ * 16);
    const int lr = lane & 15, lq = lane >> 4;
    const int swz = lr & 7;

    const ushort* srcA[4]; int dstOffA[4];
    const ushort* srcB[NJ]; int dstOffB[NJ];
#pragma unroll
    for (int p = 0; p < 4; p++) {
        int slt = p * 256 + tid;
        int row = slt >> 3, cb = (slt & 7) ^ (row & 7);
        srcA[p] = A + (size_t)(bm * 128 + row) * 1024 + cb * 8;
        dstOffA[p] = p * 2048 + wave * 512;
    }
#pragma unroll
    for (int p = 0; p < NJ; p++) {
        int slt = p * 256 + tid;
        int row = slt >> 3, cb = (slt & 7) ^ (row & 7);
        srcB[p] = BT + (size_t)(bn * BNT + row) * 1024 + cb * 8;
        dstOffB[p] = p * 2048 + wave * 512;
    }

    f32x4 acc[4][NJ];
#pragma unroll
    for (int ii = 0; ii < 4; ii++)
#pragma unroll
        for (int j = 0; j < NJ; j++) acc[ii][j] = (f32x4){0.f, 0.f, 0.f, 0.f};

#pragma unroll
    for (int p = 0; p < 4; p++) gll16(srcA[p], &As[dstOffA[p]]);
#pragma unroll
    for (int p = 0; p < NJ; p++) gll16(srcB[p], &Bs[dstOffB[p]]);

    for (int kt = 0; kt < 16; kt++) {
        __syncthreads();
        if (kt < 15) {
            int buf = (kt + 1) & 1, ko = (kt + 1) * 64;
#pragma unroll
            for (int p = 0; p < 4; p++)
                gll16(srcA[p] + ko, &As[buf * 8192 + dstOffA[p]]);
#pragma unroll
            for (int p = 0; p < NJ; p++)
                gll16(srcB[p] + ko, &Bs[buf * (NJ * 2048) + dstOffB[p]]);
        }
        const ushort* as = As + (kt & 1) * 8192;
        const ushort* bs = Bs + (kt & 1) * (NJ * 2048);
        bf16x8 af[2][4], bfr[2][NJ];
#pragma unroll
        for (int kh = 0; kh < 2; kh++) {
#pragma unroll
            for (int ii = 0; ii < 4; ii++)
                af[kh][ii] = *(const bf16x8*)&as[(wm + ii * 16 + lr) * 64 + ((kh * 4 + lq) ^ swz) * 8];
#pragma unroll
            for (int j = 0; j < NJ; j++)
                bfr[kh][j] = *(const bf16x8*)&bs[(wn + j * 16 + lr) * 64 + ((kh * 4 + lq) ^ swz) * 8];
        }
#pragma unroll
        for (int kh = 0; kh < 2; kh++)
#pragma unroll
            for (int ii = 0; ii < 4; ii++)
#pragma unroll
                for (int j = 0; j < NJ; j++)
                    acc[ii][j] = __builtin_amdgcn_mfma_f32_16x16x32_bf16(af[kh][ii], bfr[kh][j], acc[ii][j], 0, 0, 0);
    }

#pragma unroll
    for (int ii = 0; ii < 4; ii++) {
        int mg = bm * 128 + wm + ii * 16 + lq * 4;
#pragma unroll
        for (int j = 0; j < NJ; j++) {
            int cg = bn * BNT + wn + j * 16 + lr;
            float bv = bias[cg];
#pragma unroll
            for (int r = 0; r < 4; r++)
                outF[(size_t)(mg + r) * DM + cg] = acc[ii][j][r] + bv;
        }
    }
}

// ---------------------------------------------------------------------------
// Attention (R1-exact, best known 43.5 us): 512 blocks, XCD-local.
// Block = 128 q x full key sweep in 128-key tiles (16 iters). 4 waves 2x2.
// gll16 dbuf LDS 64 KB (K 128x64, V^T 64x128), 2 blocks/CU.
// ---------------------------------------------------------------------------
__global__ __launch_bounds__(256, 2) void gqa_attn_kernel(
        const ushort* __restrict__ Qb, const ushort* __restrict__ Kb,
        const ushort* __restrict__ Vtg, ushort* __restrict__ ctx)
{
    __shared__ ushort Ks[2][128 * 64];   // 32 KB
    __shared__ ushort Vs[2][64 * 128];   // 32 KB

    const int tid = threadIdx.x, wave = tid >> 6, lane = tid & 63;
    const int lr = lane & 15, lq = lane >> 4;
    const int swz = lr & 7;
    const int wq = wave & 1, wt = wave >> 1;
    const int i = blockIdx.x;
    const int bg = i & 7, s2 = i >> 3;
    const int qt = s2 & 15, h = s2 >> 4;
    const int b = bg >> 2, g = bg & 3, hg = g * 4 + h;

    const ushort* Qh = Qb  + (size_t)(b * NHEADS  + hg) * SEQ * DK;
    const ushort* Kg = Kb  + (size_t)(b * NGROUPS + g)  * SEQ * DK;
    const ushort* Vg = Vtg + (size_t)(b * NGROUPS + g)  * DK * SEQ;

    const int s0 = qt * 128 + wq * 64;
    const int tb = wt * 64;              // wave's t-stripe base within tile

    bf16x8 qf[4][2];
#pragma unroll
    for (int qs = 0; qs < 4; qs++)
#pragma unroll
        for (int kh = 0; kh < 2; kh++)
            qf[qs][kh] = *(const bf16x8*)(Qh + (size_t)(s0 + qs * 16 + lr) * DK + kh * 32 + lq * 8);

    // staging: K 4 slots (row = slot>>3 in 0..127, 8 chunks/row);
    //          V 4 slots (row = slot>>4 in 0..63, 16 chunks/row, XOR low-3)
    const ushort* srcK[4]; const ushort* srcV[4]; int dstOff[4];
#pragma unroll
    for (int p = 0; p < 4; p++) {
        int slt = p * 256 + tid;
        int krow = slt >> 3, kcb = (slt & 7) ^ (krow & 7);
        srcK[p] = Kg + (size_t)krow * DK + kcb * 8;
        int vrow = slt >> 4, vc = slt & 15;
        int vcb = (vc & 8) | ((vc ^ vrow) & 7);
        srcV[p] = Vg + (size_t)vrow * SEQ + vcb * 8;
        dstOff[p] = (p * 256 + wave * 64) * 8;   // ushort offset; lane*8 added by HW
    }

    f32x4 of[4][4];
#pragma unroll
    for (int qs = 0; qs < 4; qs++)
#pragma unroll
        for (int j = 0; j < 4; j++) of[qs][j] = (f32x4){0.f, 0.f, 0.f, 0.f};
    f32x4 accL[4];
#pragma unroll
    for (int qs = 0; qs < 4; qs++) accL[qs] = (f32x4){0.f, 0.f, 0.f, 0.f};

    bf16x8 ones;
#pragma unroll
    for (int k = 0; k < 8; k++) ones[k] = (short)0x3F80;

#pragma unroll
    for (int p = 0; p < 4; p++) {
        gll16(srcK[p], &Ks[0][dstOff[p]]);
        gll16(srcV[p], &Vs[0][dstOff[p]]);
    }

    for (int it = 0; it < 16; it++) {
        __syncthreads();
        if (it < 15) {
            int buf = (it + 1) & 1, t0 = (it + 1) * 128;
#pragma unroll
            for (int p = 0; p < 4; p++) {
                gll16(srcK[p] + (size_t)t0 * DK, &Ks[buf][dstOff[p]]);
                gll16(srcV[p] + t0, &Vs[buf][dstOff[p]]);
            }
        }
        const ushort* ks = Ks[it & 1];
        const ushort* vs = Vs[it & 1];

        bf16x8 kf[4][2];
#pragma unroll
        for (int nt = 0; nt < 4; nt++)
#pragma unroll
            for (int kh = 0; kh < 2; kh++)
                kf[nt][kh] = *(const bf16x8*)&ks[(tb + nt * 16 + lr) * 64 + ((kh * 4 + lq) ^ swz) * 8];

        bf16x8 vf[4][2];
#pragma unroll
        for (int j = 0; j < 4; j++)
#pragma unroll
            for (int kk = 0; kk < 2; kk++)
                vf[j][kk] = *(const bf16x8*)&vs[(j * 16 + lr) * 128 + (wt * 8 + ((kk * 4 + lq) ^ swz)) * 8];

        // S^T[t][q] over the wave's 64-t stripe (Q pre-scaled -> log2 domain)
        f32x4 sc[4][4];
#pragma unroll
        for (int qs = 0; qs < 4; qs++)
#pragma unroll
            for (int nt = 0; nt < 4; nt++) {
                f32x4 s = (f32x4){0.f, 0.f, 0.f, 0.f};
                s = __builtin_amdgcn_mfma_f32_16x16x32_bf16(kf[nt][0], qf[qs][0], s, 0, 0, 0);
                s = __builtin_amdgcn_mfma_f32_16x16x32_bf16(kf[nt][1], qf[qs][1], s, 0, 0, 0);
                sc[qs][nt] = s;
            }

        // exp2 -> truncate-pack into two K=32 B-frags per qs; sums via ones-MFMA
        union PF { bf16x8 v; uint32_t w[4]; };
        PF pf[4][2];
#pragma unroll
        for (int qs = 0; qs < 4; qs++) {
#pragma unroll
            for (int nt = 0; nt < 4; nt++) {
                union { float f; uint32_t u; } e0, e1, e2, e3;
                e0.f = __builtin_amdgcn_exp2f(sc[qs][nt][0]);
                e1.f = __builtin_amdgcn_exp2f(sc[qs][nt][1]);
                e2.f = __builtin_amdgcn_exp2f(sc[qs][nt][2]);
                e3.f = __builtin_amdgcn_exp2f(sc[qs][nt][3]);
                pf[qs][nt >> 1].w[(nt & 1) * 2 + 0] = __builtin_amdgcn_perm(e1.u, e0.u, 0x07060302u);
                pf[qs][nt >> 1].w[(nt & 1) * 2 + 1] = __builtin_amdgcn_perm(e3.u, e2.u, 0x07060302u);
            }
            accL[qs] = __builtin_amdgcn_mfma_f32_16x16x32_bf16(ones, pf[qs][0].v, accL[qs], 0, 0, 0);
            accL[qs] = __builtin_amdgcn_mfma_f32_16x16x32_bf16(ones, pf[qs][1].v, accL[qs], 0, 0, 0);
        }

        // O^T[d][q] += V^T(stripe) · P
#pragma unroll
        for (int qs = 0; qs < 4; qs++)
#pragma unroll
            for (int j = 0; j < 4; j++) {
                of[qs][j] = __builtin_amdgcn_mfma_f32_16x16x32_bf16(vf[j][0], pf[qs][0].v, of[qs][j], 0, 0, 0);
                of[qs][j] = __builtin_amdgcn_mfma_f32_16x16x32_bf16(vf[j][1], pf[qs][1].v, of[qs][j], 0, 0, 0);
            }
    }

    // ---- combine t-halves (wt=1 -> LDS overlay -> wt=0 adds) ----
    __syncthreads();                       // all staging reads done; overlay safe
    float* comb = (float*)&Ks[0][0];       // 32 KB: [wq][(qs*4+j)*256 + lane*4]
    float* accX = (float*)&Vs[0][0];       // [ (wq*4+qs)*16 + lr ]
    if (wt == 1) {
        float* cw = comb + wq * 4096;
#pragma unroll
        for (int qs = 0; qs < 4; qs++)
#pragma unroll
            for (int j = 0; j < 4; j++)
                *(f32x4*)&cw[(qs * 4 + j) * 256 + lane * 4] = of[qs][j];
        if (lq == 0) {
#pragma unroll
            for (int qs = 0; qs < 4; qs++) accX[(wq * 4 + qs) * 16 + lr] = accL[qs][0];
        }
    }
    __syncthreads();
    if (wt == 0) {
        const float* cw = comb + wq * 4096;
        float inv[4];
#pragma unroll
        for (int qs = 0; qs < 4; qs++)
            inv[qs] = 1.0f / (accL[qs][0] + accX[(wq * 4 + qs) * 16 + lr]);
        ushort* cbp = ctx + (size_t)b * SEQ * DM;
#pragma unroll
        for (int qs = 0; qs < 4; qs++) {
            int s = s0 + qs * 16 + lr;
#pragma unroll
            for (int j = 0; j < 4; j++) {
                f32x4 o2 = of[qs][j] + *(const f32x4*)&cw[(qs * 4 + j) * 256 + lane * 4];
                ushort4 o;
                o.x = f2bf(o2[0] * inv[qs]);
                o.y = f2bf(o2[1] * inv[qs]);
                o.z = f2bf(o2[2] * inv[qs]);
                o.w = f2bf(o2[3] * inv[qs]);
                *(ushort4*)(cbp + (size_t)s * DM + hg * 64 + j * 16 + lq * 4) = o;
            }
        }
    }
}

// ---------------------------------------------------------------------------
extern "C" void kernel_launch(void* const* d_in, const int* in_sizes, int n_in,
                              void* d_out, int out_size, void* d_ws, size_t ws_size,
                              hipStream_t stream) {
    const float* x  = (const float*)d_in[0];
    const float* WQ = (const float*)d_in[1];
    const float* bQ = (const float*)d_in[2];
    const float* WK = (const float*)d_in[3];
    const float* bK = (const float*)d_in[4];
    const float* WV = (const float*)d_in[5];
    const float* bV = (const float*)d_in[6];
    const float* WO = (const float*)d_in[7];
    const float* bO = (const float*)d_in[8];

    ushort* Qb    = (ushort*)d_ws;
    ushort* Kb    = Qb + QB_ELEMS;
    ushort* Vtg   = Kb + KB_ELEMS;
    ushort* xc    = Vtg + VT_ELEMS;       // xbf (QKV input), later reused as ctx
    ushort* WqkvT = xc + XC_ELEMS;
    ushort* WoT   = WqkvT + WQKV_ELEMS;
    float*  bcat  = (float*)(WoT + WO_ELEMS);

    gqa_prep_kernel<<<641, 256, 0, stream>>>(x, WQ, WK, WV, bQ, bK, bV,
                                             xc, WqkvT, bcat);
    // QKV: 256 riders + 32x12 = 640 blocks (128x128 tiles, N=1536)
    gqa_qkv_kernel<12><<<640, 256, 0, stream>>>(
        xc, WqkvT, bcat, Qb, Kb, Vtg, WO, WoT);
    gqa_attn_kernel<<<512, 256, 0, stream>>>(Qb, Kb, Vtg, xc);
    // O-proj: 32x16 = 512 tiles of 128x64 (2 blocks/CU, no atomics)
    gqa_oproj_kernel<<<512, 256, 0, stream>>>(xc, WoT, bO, (float*)d_out);
}